// Round 10
// baseline (246.998 us; speedup 1.0000x reference)
//
#include <hip/hip_runtime.h>
#include <hip/hip_bf16.h>
#include <cstdint>
#include <cstddef>

typedef __attribute__((ext_vector_type(4))) float f32x4;
typedef __attribute__((ext_vector_type(8))) short bf16x8;
typedef unsigned short ushort_t;

#define KDIM 768
#define GQ 96       // KDIM/8 granules
#define BM 64
#define BN 64
#define BK 32
#define NKT 24      // 768/32

static __device__ __forceinline__ float sani(float x) {
  if (__builtin_isnan(x)) return 0.0f;
  if (__builtin_isinf(x)) return x > 0.0f ? 1.0e4f : -1.0e4f;
  return x;
}

static __device__ __forceinline__ unsigned short f2bf(float x) {
  unsigned u = __builtin_bit_cast(unsigned, x);
  unsigned r = 0x7FFFu + ((u >> 16) & 1u);
  return (unsigned short)((u + r) >> 16);
}

// xl: PLAIN row-major [1024][768] bf16 (A; staged with per-lane pre-swizzled
//     sources -> R7's measured-0-conflict LDS layout).
// wt: K-major-tiled [g 0..95][Vpad rows][8] bf16 (B; direct global->reg).

__global__ __launch_bounds__(256) void prep_x_kernel(
    const float* __restrict__ h, ushort_t* __restrict__ xl,
    float* __restrict__ tx) {
  const int row = blockIdx.x;
  const int t = threadIdx.x;
  const float* src = h + (size_t)row * (KDIM + 1) + 1;  // skip time comp
  float v0 = sani(src[t]);
  float v1 = sani(src[t + 256]);
  float v2 = sani(src[t + 512]);
  float ss = v0 * v0 + v1 * v1 + v2 * v2;
#pragma unroll
  for (int off = 32; off > 0; off >>= 1) ss += __shfl_down(ss, off);
  __shared__ float red[4];
  if ((t & 63) == 0) red[t >> 6] = ss;
  __syncthreads();
  if (t == 0) {
    float total = red[0] + red[1] + red[2] + red[3];
    tx[row] = sqrtf(1.0f + total);
  }
  ushort_t* dst = xl + (size_t)row * KDIM;
  dst[t]       = f2bf(v0);
  dst[t + 256] = f2bf(v1);
  dst[t + 512] = f2bf(v2);
}

__global__ __launch_bounds__(256) void prep_w_kernel(
    const float* __restrict__ w, ushort_t* __restrict__ wt,
    float* __restrict__ cw, int V, int Vpad) {
  __shared__ float fs[8 * KDIM];  // 24 KB
  __shared__ float redv[8], scs[8];
  const int t = threadIdx.x;
  const int r = t >> 5, j = t & 31;
  const int row = blockIdx.x * 8 + r;
  const bool valid = row < V;
  const float* src = w + (size_t)row * KDIM;
  float ss = 0.0f;
#pragma unroll
  for (int k = 0; k < 24; ++k) {
    float v = valid ? src[j + 32 * k] : 0.0f;
    fs[r * KDIM + j + 32 * k] = v;
    ss = fmaf(v, v, ss);
  }
#pragma unroll
  for (int m = 16; m > 0; m >>= 1) ss += __shfl_xor(ss, m);
  if (j == 0) redv[r] = ss;
  __syncthreads();
  if (t < 8) {
    const int rw = blockIdx.x * 8 + t;
    float rr = sqrtf(redv[t]);
    float rc = fminf(rr, 3.0f);
    float e = expf(rc), ei = 1.0f / e;
    scs[t] = (rw < V) ? 0.5f * (e - ei) / fmaxf(rr, 1e-8f) : 0.0f;
    cw[rw] = (rw < V) ? sani(0.5f * (e + ei)) : 0.0f;
  }
  __syncthreads();
#pragma unroll
  for (int p = 0; p < 3; ++p) {
    const int c = t + 256 * p;   // 768 chunks: g = c>>3, local row = c&7
    const int g = c >> 3, rl = c & 7;
    const float sc = scs[rl];
    ushort_t pk[8];
#pragma unroll
    for (int e = 0; e < 8; ++e)
      pk[e] = f2bf(sani(fs[rl * KDIM + g * 8 + e] * sc));
    *(uint4*)&wt[((size_t)g * Vpad + blockIdx.x * 8 + rl) * 8] =
        *(const uint4*)pk;
  }
}

#define GLD16(gp, sp)                                               \
  __builtin_amdgcn_global_load_lds(                                 \
      (const __attribute__((address_space(1))) void*)(gp),          \
      (__attribute__((address_space(3))) void*)(sp), 16, 0, 0)

// Zero-barrier GEMM: one wave per block, 64x64 tile, BK=32.
// A: LDS dbuf 2 x 4 KB via global_load_lds (R7-verified swizzled layout).
// B: K-major wt, global->reg, ping-pong regs. One counted vmcnt(8)/K-step.
// No s_barrier at all; 16 independent waves/CU provide all overlap.
__global__ __launch_bounds__(64, 4) void gemm_kernel(
    const ushort_t* __restrict__ xl, const ushort_t* __restrict__ wt,
    const float* __restrict__ tx, const float* __restrict__ cw,
    const float* __restrict__ ls, float* __restrict__ out,
    int V, int Vpad, int nwg8) {
  __shared__ ushort_t lds[2 * 2048];  // 2 slots x 4 KB

  const int lane = threadIdx.x;
  const int l15 = lane & 15;
  const int lq = lane >> 4;  // 0..3

  // chunked XCD swizzle (nwg % 8 == 0); bm fastest -> 16 L share a B-panel
  const int g = blockIdx.x;
  const int L = (g & 7) * nwg8 + (g >> 3);
  const int bm = L & 15;
  const int bn = L >> 4;

  const int a_row0 = bm * BM;
  const int b_row0 = bn * BN;

  // ---- A staging sources (inverse of swizzled LDS layout; R7-verified) ----
  const int ggl = (lane & 7) ^ (lane >> 3);
  const int rl = 2 * (lane >> 3) + (ggl >> 2);
  const int cg = (ggl & 3) * 8;
  const ushort_t* pc0 = xl + (size_t)(a_row0 + 0  + rl) * KDIM + cg;
  const ushort_t* pc1 = xl + (size_t)(a_row0 + 16 + rl) * KDIM + cg;
  const ushort_t* pc2 = xl + (size_t)(a_row0 + 32 + rl) * KDIM + cg;
  const ushort_t* pc3 = xl + (size_t)(a_row0 + 48 + rl) * KDIM + cg;

  // ---- A ds_read offsets (ushort elements) ----
  const int rphys = l15 >> 1;
  const int gph = (((l15 & 1) << 2) + lq) ^ rphys;
  const int aoff = rphys * 64 + gph * 8;

  // ---- B fragment base (K-major wt) ----
  const ushort_t* bp = wt + ((size_t)lq * Vpad + b_row0 + l15) * 8;
  const size_t BSTEP = (size_t)4 * Vpad * 8;  // 4 granules per K-step

  f32x4 acc[4][4];
#pragma unroll
  for (int i = 0; i < 4; ++i)
#pragma unroll
    for (int j = 0; j < 4; ++j) acc[i][j] = (f32x4){0.f, 0.f, 0.f, 0.f};

  bf16x8 af[4], bfA[4], bfB[4];

#define STAGE_A(T_, S_)                                                       \
  {                                                                           \
    GLD16(pc0 + (T_) * BK, &lds[(S_) * 2048 + 0 * 512]);                      \
    GLD16(pc1 + (T_) * BK, &lds[(S_) * 2048 + 1 * 512]);                      \
    GLD16(pc2 + (T_) * BK, &lds[(S_) * 2048 + 2 * 512]);                      \
    GLD16(pc3 + (T_) * BK, &lds[(S_) * 2048 + 3 * 512]);                      \
  }

#define LOADB(T_, D_)                                                         \
  {                                                                           \
    const ushort_t* p_ = bp + (size_t)(T_) * BSTEP;                           \
    D_[0] = *(const bf16x8*)(p_);                                             \
    D_[1] = *(const bf16x8*)(p_ + 128);                                       \
    D_[2] = *(const bf16x8*)(p_ + 256);                                       \
    D_[3] = *(const bf16x8*)(p_ + 384);                                       \
  }

#define READ_A(S_)                                                            \
  _Pragma("unroll") for (int mi = 0; mi < 4; ++mi)                            \
      af[mi] = *(const bf16x8*)&lds[(S_) * 2048 + mi * 512 + aoff];

#define MFMA16(CB_)                                                           \
  _Pragma("unroll") for (int mi = 0; mi < 4; ++mi)                            \
    _Pragma("unroll") for (int ni = 0; ni < 4; ++ni)                          \
        acc[mi][ni] = __builtin_amdgcn_mfma_f32_16x16x32_bf16(                \
            CB_[ni], af[mi], acc[mi][ni], 0, 0, 0);

  // ITER: prefetch (t+1), counted vmcnt certifies (t)'s stage+B, compute (t).
  // Single wave: in-order issue makes slot reuse safe without barriers;
  // compiler auto-inserts lgkmcnt for the ds_read->MFMA dependency.
#define ITER(T_, S_, CB_, NB_)                                                \
  {                                                                           \
    STAGE_A((T_) + 1, (S_) ^ 1);                                              \
    LOADB((T_) + 1, NB_);                                                     \
    asm volatile("s_waitcnt vmcnt(8)" ::: "memory");                          \
    READ_A(S_);                                                               \
    MFMA16(CB_);                                                              \
  }

  STAGE_A(0, 0);
  LOADB(0, bfA);

#pragma unroll 1
  for (int tt = 0; tt < 11; ++tt) {
    const int t0 = 2 * tt;
    ITER(t0, 0, bfA, bfB);
    ITER(t0 + 1, 1, bfB, bfA);
  }
  // t = 22: prefetch 23
  ITER(22, 0, bfA, bfB);
  // t = 23: drain
  asm volatile("s_waitcnt vmcnt(0)" ::: "memory");
  READ_A(1);
  MFMA16(bfB);

  float tau = ls[0];
  tau = fminf(fmaxf(tau, 0.01f), 2.5f);

  // swapped-operand C/D: m = l15 (col field), n = lq*4 + j (row field)
#pragma unroll
  for (int mi = 0; mi < 4; ++mi) {
    const int mg = a_row0 + mi * 16 + l15;
    const float txm = tx[mg];
    float* orow = out + (size_t)mg * V;
#pragma unroll
    for (int ni = 0; ni < 4; ++ni) {
      const int nb = b_row0 + ni * 16 + lq * 4;
      const f32x4 cw4 = *(const f32x4*)&cw[nb];
      f32x4 v;
#pragma unroll
      for (int j = 0; j < 4; ++j)
        v[j] = (acc[mi][ni][j] - txm * cw4[j]) * tau;
      if (nb + 3 < V) {
        __builtin_memcpy(&orow[nb], &v, 16);
      } else {
#pragma unroll
        for (int j = 0; j < 4; ++j)
          if (nb + j < V) orow[nb + j] = v[j];
      }
    }
  }
#undef STAGE_A
#undef LOADB
#undef READ_A
#undef MFMA16
#undef ITER
}

extern "C" void kernel_launch(void* const* d_in, const int* in_sizes, int n_in,
                              void* d_out, int out_size, void* d_ws, size_t ws_size,
                              hipStream_t stream) {
  const float* h = (const float*)d_in[0];
  const float* w = (const float*)d_in[1];
  const float* ls = (const float*)d_in[2];
  float* out = (float*)d_out;

  const int M = in_sizes[0] / (KDIM + 1);        // 1024
  const int V = in_sizes[1] / KDIM;              // 50257
  const int Vpad = (V + BN - 1) & ~(BN - 1);     // 50304

  // ws: wt bf16 [96*Vpad*8] | xl bf16 [M*768] | cw f32 [Vpad] | tx f32 [M]
  char* ws = (char*)d_ws;
  ushort_t* wt = (ushort_t*)ws;
  ushort_t* xl = (ushort_t*)(ws + (size_t)GQ * Vpad * 8 * 2);
  float* cw = (float*)(ws + (size_t)GQ * Vpad * 8 * 2 + (size_t)M * KDIM * 2);
  float* tx = cw + Vpad;

  prep_x_kernel<<<dim3(M), dim3(256), 0, stream>>>(h, xl, tx);
  prep_w_kernel<<<dim3(Vpad / 8), dim3(256), 0, stream>>>(w, wt, cw, V, Vpad);

  const int nwg = (M / BM) * (Vpad / BN);        // 16 * 786 = 12576 (div by 8)
  gemm_kernel<<<dim3(nwg), dim3(64), 0, stream>>>(
      xl, wt, tx, cw, ls, out, V, Vpad, nwg / 8);
}